// Round 18
// baseline (59.941 us; speedup 1.0000x reference)
//
#include <hip/hip_runtime.h>
#include <hip/hip_fp16.h>

#define R_    1024
#define B_    4
#define C_    256
#define H_    64
#define W_    64
#define HW_   4096
#define PHW_  49
#define ROIT  128      // floats per per-ROI wy/meta record (512 B)
#define LROWH 130      // fixup LDS row halves (128 + 2 pad)
#define TROW  260      // prep-transpose LDS row halves (256 + 4 pad)
#define SLACKH 17408   // zeroed halves after fTh (covers pipeline overrun; worst 17152+248)

__device__ __forceinline__ void cell_w(float start, float end, float s, float& g0, float& g1) {
    float y0 = fmaxf(start, s);
    float yl = fmaxf(fminf(end, s + 1.0f), y0);
    float a  = y0 - s;
    float la = yl - s;
    g0 = la - 0.5f * la * la - a + 0.5f * a * a;
    g1 = 0.5f * la * la - 0.5f * a * a;
}

// ---- prep: transpose (B,C,H,W) f32 -> (B,H*W,C) f16 [0..511]
//            + ROI sort / slack-zero [512] + per-bin geometry [513..708] ----
__global__ __launch_bounds__(256) void prep(const float* __restrict__ in,
                                            __half* __restrict__ fTh,
                                            const float* __restrict__ rois,
                                            int* __restrict__ perm,
                                            float* __restrict__ roitab) {
    int bid = blockIdx.x;
    if (bid < 512) {
        __shared__ __align__(16) __half lds_t[32 * TROW];
        int b  = bid >> 7;
        int p0 = (bid & 127) * 32;
        int tx = threadIdx.x & 31;
        int ty = threadIdx.x >> 5;
        const float* src = in + (size_t)b * C_ * HW_ + p0 + tx;
#pragma unroll
        for (int i = 0; i < 32; ++i) {
            int c = ty * 32 + i;
            lds_t[tx * TROW + c] = __float2half(src[(size_t)c * HW_]);
        }
        __syncthreads();
#pragma unroll
        for (int u = 0; u < 8; ++u) {
            int e = threadIdx.x + u * 256;
            int p = e >> 6;
            int q = e & 63;
            uint2 v = *(const uint2*)&lds_t[p * TROW + q * 4];
            *(uint2*)(fTh + ((size_t)b * HW_ + p0 + p) * C_ + q * 4) = v;
        }
        return;
    }
    if (bid == 512) {
        if (threadIdx.x >= 64) {
            for (int j = threadIdx.x - 64; j < SLACKH; j += 192)
                fTh[(size_t)B_ * HW_ * C_ + j] = __half(0.0f);
            return;
        }
        // 1 wave: ballot-based stable counting sort by (batch, y-band). Deterministic.
        int lane = threadIdx.x;
        unsigned long long below = (1ull << lane) - 1ull;
        int key[16];
#pragma unroll
        for (int i = 0; i < 16; ++i) {
            int idx = i * 64 + lane;
            const float* roi = rois + idx * 5;
            int b = (int)roi[0];
            float yc = (roi[2] + roi[4]) * 0.5f * 0.0625f;
            int yb = min(3, max(0, (int)(yc * 0.0625f)));
            key[i] = b * 4 + yb;
        }
        int cntk[16];
#pragma unroll
        for (int k = 0; k < 16; ++k) cntk[k] = 0;
        for (int i = 0; i < 16; ++i)
#pragma unroll
            for (int k = 0; k < 16; ++k)
                cntk[k] += __popcll(__ballot(key[i] == k));
        int off[16]; int acc = 0;
#pragma unroll
        for (int k = 0; k < 16; ++k) { off[k] = acc; acc += cntk[k]; }
        for (int i = 0; i < 16; ++i) {
#pragma unroll
            for (int k = 0; k < 16; ++k) {
                unsigned long long m = __ballot(key[i] == k);
                if (key[i] == k)
                    perm[off[k] + __popcll(m & below)] = i * 64 + lane;
                off[k] += __popcll(m);
            }
        }
        return;
    }
    // per-bin geometry -> rtab
    int i = (bid - 513) * 256 + threadIdx.x;   // 0..50175
    int r  = i / PHW_;
    int k  = i - r * PHW_;
    int ph = k / 7, pw = k - ph * 7;
    const float* roi = rois + r * 5;
    int bb = (int)roi[0];
    float x1 = roi[1] * 0.0625f, y1 = roi[2] * 0.0625f;
    float x2 = roi[3] * 0.0625f, y2 = roi[4] * 0.0625f;
    float rw = fmaxf(x2 - x1, 0.0f), rh = fmaxf(y2 - y1, 0.0f);
    float bw = rw / 7.0f, bh = rh / 7.0f;
    float win = bw * bh;
    float* rt = roitab + (size_t)r * ROIT;

    float wy[8], wx[7];
#pragma unroll
    for (int t = 0; t < 7; ++t) { wy[t] = 0.0f; wx[t] = 0.0f; }
    wy[7] = 0.0f;
    int w0 = 0, h0 = 0, npy = 0, w00 = 0;
    float invwin = 0.0f;
    if (win > 0.0f) {
        float ws = x1 + bw * (float)pw, we = ws + bw;
        float hs = y1 + bh * (float)ph, he = hs + bh;
        float s0w = floorf(ws), s0h = floorf(hs);
        w0 = (int)s0w; h0 = (int)s0h;
        w00 = (int)floorf(x1);
#pragma unroll
        for (int o = 0; o < 6; ++o) {
            float g0, g1;
            cell_w(hs, he, s0h + (float)o, g0, g1);
            wy[o] += g0; wy[o + 1] += g1;
            cell_w(ws, we, s0w + (float)o, g0, g1);
            wx[o] += g0; wx[o + 1] += g1;
        }
        npy = min(7, max(0, (int)ceilf(he - s0h + 1.0f)));
        int npx = min(7, max(0, (int)ceilf(we - s0w + 1.0f)));
        npy = max(0, min(npy, H_ - h0));
        npx = max(0, min(npx, W_ - w0));
#pragma unroll
        for (int t = 0; t < 7; ++t) {
            if (t >= npx) wx[t] = 0.0f;
            if (t >= npy) wy[t] = 0.0f;
        }
        invwin = 1.0f / win;
    }
    if (ph == 0) {
#pragma unroll
        for (int t = 0; t < 7; ++t) rt[pw * 7 + t] = wx[t];
        rt[49 + pw] = __int_as_float(w0 - w00);
    }
    if (pw == 0) {
#pragma unroll
        for (int t = 0; t < 8; ++t) rt[72 + ph * 8 + t] = wy[t] * invwin;   // slot 7 = 0
        rt[64 + ph] = __int_as_float(h0 | (npy << 8));
    }
    if (k == 0) {
        int jlim = 0;
        if (win > 0.0f) {
#pragma unroll
            for (int p = 0; p < 7; ++p) {
                float wsp = x1 + bw * (float)p, wep = wsp + bw;
                float s0wp = floorf(wsp);
                int w0p = (int)s0wp;
                int npxp = min(7, max(0, (int)ceilf(wep - s0wp + 1.0f)));
                npxp = max(0, min(npxp, W_ - w0p));
                jlim = max(jlim, (w0p - w00) + npxp);
            }
        }
        rt[63] = __int_as_float(bb | (w00 << 8) | (jlim << 16));
    }
}

// ---- compute: one wave per (ROI, bin-row); fully-pipelined (jl,dy) stream.
// Rolling one-item-ahead prefetch crosses the jl boundary, so the next
// column-pair's loads are in flight during the APPLY stage.
__global__ __launch_bounds__(256) void prroi_rows(const __half* __restrict__ fTh,
                                                  const int* __restrict__ perm,
                                                  const float* __restrict__ roitab,
                                                  __half* __restrict__ scr) {
    __shared__ __align__(16) float colw[4][32 * 8];
    int wid  = __builtin_amdgcn_readfirstlane(threadIdx.x >> 6);
    int lane = threadIdx.x & 63;
    float* cwv = colw[wid];
    int bid = blockIdx.x;                 // 2048 blocks
    int xcd = bid & 7;
    int s   = (bid >> 3) * 4 + wid;       // 0..1023 slot within XCD
    if (s >= 896) return;
    int t   = (s & 31) * 28 + (s >> 5);   // stride-spread bijection over [0,896)
    int g   = xcd * 896 + t;
    int rs  = g / 7;
    int ph  = g - rs * 7;
    int r   = __builtin_amdgcn_readfirstlane(perm[rs]);
    const float* rt = roitab + (size_t)r * ROIT;

#pragma unroll
    for (int u = 0; u < 4; ++u) cwv[lane + u * 64] = 0.0f;
    if (lane < 49) {
        int pw = lane / 7;
        int dx = lane - pw * 7;
        float wxv = rt[lane];
        int d = __float_as_int(rt[49 + pw]);
        cwv[(d + dx) * 8 + pw] = wxv;     // unique (col,pw) per lane
    }
    int meta = __float_as_int(rt[63]);
    int bb   = meta & 0xff;
    int w00  = (meta >> 8) & 0xff;
    int jlim = (meta >> 16) & 0xff;
    int hm   = __float_as_int(rt[64 + ph]);
    int h0   = hm & 0xff;
    int npy  = (hm >> 8) & 0xff;
    int npy2 = (npy + 1) & ~1;            // extra row has wy=0; lands in slack
    const float* wyp = rt + 72 + ph * 8;

    int half = lane >> 5;
    int cl   = lane & 31;
    const __half* fr = fTh + ((size_t)bb * HW_ + (size_t)h0 * W_ + w00 + half) * C_ + cl * 8;

    float4 aA[7], aB[7];
#pragma unroll
    for (int p = 0; p < 7; ++p) {
        aA[p] = make_float4(0.f, 0.f, 0.f, 0.f);
        aB[p] = make_float4(0.f, 0.f, 0.f, 0.f);
    }

    int ndy = npy2 >> 1;                  // row-pairs per column-pair
    int njl = (jlim + 1) >> 1;            // column-pairs
    const int ROWSTEP = 2 * W_ * C_;      // 2 feature rows
    const int COLSTEP = 2 * C_;           // 2 feature columns

    // prime the pipeline: first item (jp=0, dp=0)
    uint4 va = *(const uint4*)(fr);
    uint4 vb = *(const uint4*)(fr + W_ * C_);

    for (int jp = 0; jp < njl; ++jp) {
        const float* cw = cwv + (jp * 2 + half) * 8;
        float4 c0 = *(const float4*)(cw);              // coefs p0..3 for my column
        float4 c1 = *(const float4*)(cw + 4);          // coefs p4..6
        const __half* cp = fr + (size_t)jp * COLSTEP;
        __half2 g0 = __float2half2_rn(0.0f), g1 = g0, g2 = g0, g3 = g0;
        for (int dp = 0; dp < ndy; ++dp) {
            // prefetch next item: (jp, dp+1) or (jp+1, 0) at the boundary.
            // Final overrun (jp==njl) is address-safe (slack) and discarded.
            int nd = dp + 1;
            const __half* rn = (nd == ndy) ? (cp + COLSTEP)
                                           : (cp + (size_t)nd * ROWSTEP);
            uint4 na = *(const uint4*)(rn);
            uint4 nb = *(const uint4*)(rn + W_ * C_);
            __half2 w0h = __float2half2_rn(wyp[2 * dp]);       // uniform scalar loads
            __half2 w1h = __float2half2_rn(wyp[2 * dp + 1]);   // zeroed beyond npy
            g0 = __hfma2(w0h, *(__half2*)&va.x, g0);
            g1 = __hfma2(w0h, *(__half2*)&va.y, g1);
            g2 = __hfma2(w0h, *(__half2*)&va.z, g2);
            g3 = __hfma2(w0h, *(__half2*)&va.w, g3);
            g0 = __hfma2(w1h, *(__half2*)&vb.x, g0);
            g1 = __hfma2(w1h, *(__half2*)&vb.y, g1);
            g2 = __hfma2(w1h, *(__half2*)&vb.z, g2);
            g3 = __hfma2(w1h, *(__half2*)&vb.w, g3);
            va = na; vb = nb;
        }
        float2 t0 = __half22float2(g0);
        float2 t1 = __half22float2(g1);
        float2 t2 = __half22float2(g2);
        float2 t3 = __half22float2(g3);
        float4 gA = make_float4(t0.x, t0.y, t1.x, t1.y);   // channels 8cl..8cl+3
        float4 gB = make_float4(t2.x, t2.y, t3.x, t3.y);   // channels 8cl+4..8cl+7
#define APPLY(P, CP) { \
    aA[P].x = fmaf(CP, gA.x, aA[P].x); aA[P].y = fmaf(CP, gA.y, aA[P].y); \
    aA[P].z = fmaf(CP, gA.z, aA[P].z); aA[P].w = fmaf(CP, gA.w, aA[P].w); \
    aB[P].x = fmaf(CP, gB.x, aB[P].x); aB[P].y = fmaf(CP, gB.y, aB[P].y); \
    aB[P].z = fmaf(CP, gB.z, aB[P].z); aB[P].w = fmaf(CP, gB.w, aB[P].w); }
        APPLY(0, c0.x); APPLY(1, c0.y); APPLY(2, c0.z); APPLY(3, c0.w);
        APPLY(4, c1.x); APPLY(5, c1.y); APPLY(6, c1.z);
#undef APPLY
    }

    // cross-half combine: lane l and l+32 hold same channels, different column parity
#pragma unroll
    for (int p = 0; p < 7; ++p) {
        aA[p].x += __shfl_xor(aA[p].x, 32);
        aA[p].y += __shfl_xor(aA[p].y, 32);
        aA[p].z += __shfl_xor(aA[p].z, 32);
        aA[p].w += __shfl_xor(aA[p].w, 32);
        aB[p].x += __shfl_xor(aB[p].x, 32);
        aB[p].y += __shfl_xor(aB[p].y, 32);
        aB[p].z += __shfl_xor(aB[p].z, 32);
        aB[p].w += __shfl_xor(aB[p].w, 32);
    }

    // stores: lower half writes bins 0..3, upper half bins 4..6
    __half* sb = scr + ((size_t)r * PHW_ + ph * 7) * C_ + cl * 8;
#pragma unroll
    for (int s4 = 0; s4 < 4; ++s4) {
        const int ihi = (4 + s4 > 6) ? 6 : 4 + s4;
        float4 pa = half ? aA[ihi] : aA[s4];
        float4 pb = half ? aB[ihi] : aB[s4];
        int p = half ? 4 + s4 : s4;
        if (p < 7) {
            union { __half2 h2[4]; uint4 u; } pk;
            pk.h2[0] = __floats2half2_rn(pa.x, pa.y);
            pk.h2[1] = __floats2half2_rn(pa.z, pa.w);
            pk.h2[2] = __floats2half2_rn(pb.x, pb.y);
            pk.h2[3] = __floats2half2_rn(pb.z, pb.w);
            *(uint4*)(sb + (size_t)p * C_) = pk.u;
        }
    }
}

// ---- fixup: 2 blocks per ROI (half channels); [k][c] f16 -> [c][k] f32 via padded LDS ----
__global__ __launch_bounds__(256) void fixup(const int* __restrict__ perm,
                                             const __half* __restrict__ scr,
                                             float* __restrict__ out) {
    __shared__ __align__(4) __half lds_h[PHW_ * LROWH];   // 12,740 B
    int bid  = blockIdx.x;                     // 2048
    int idx  = (bid & 7) * 256 + (bid >> 3);   // XCD-matched: rs>>7 == bid&7
    int rs   = idx >> 1;
    int half = idx & 1;
    int r    = perm[rs];
    const unsigned int* src = (const unsigned int*)(scr + (size_t)r * PHW_ * C_ + half * 128);
    for (int j = threadIdx.x; j < PHW_ * 64; j += 256) {
        int row = j >> 6;
        int col = j & 63;
        *(unsigned int*)&lds_h[row * LROWH + col * 2] = src[(size_t)row * (C_ / 2) + col];
    }
    __syncthreads();
    float* outr = out + (size_t)r * (C_ * PHW_) + (size_t)half * 128 * PHW_;
#pragma unroll 4
    for (int j = threadIdx.x; j < 128 * PHW_; j += 256) {
        int c = j / PHW_;
        int k = j - c * PHW_;
        outr[j] = __half2float(lds_h[k * LROWH + c]);
    }
}

// ---- fallback: original layout, no workspace ----
__global__ __launch_bounds__(256) void prroi_pool_direct(const float* __restrict__ f,
                                                         const float* __restrict__ rois,
                                                         float* __restrict__ out) {
    int bin = blockIdx.x;
    int r  = bin / PHW_;
    int k  = bin - r * PHW_;
    int ph = k / 7;
    int pw = k - ph * 7;
    int c = threadIdx.x;

    const float* roi = rois + r * 5;
    int bb = (int)roi[0];
    float x1 = roi[1] * 0.0625f, y1 = roi[2] * 0.0625f;
    float x2 = roi[3] * 0.0625f, y2 = roi[4] * 0.0625f;
    float rw = fmaxf(x2 - x1, 0.0f), rh = fmaxf(y2 - y1, 0.0f);
    float bw = rw / 7.0f, bh = rh / 7.0f;
    float win = bw * bh;
    size_t oidx = ((size_t)r * C_ + c) * PHW_ + k;
    if (!(win > 0.0f)) { out[oidx] = 0.0f; return; }

    float ws = x1 + bw * (float)pw, we = ws + bw;
    float hs = y1 + bh * (float)ph, he = hs + bh;
    float s0w = floorf(ws), s0h = floorf(hs);
    int w0 = (int)s0w, h0 = (int)s0h;
    float wy[7], wx[7];
#pragma unroll
    for (int t = 0; t < 7; ++t) { wy[t] = 0.0f; wx[t] = 0.0f; }
#pragma unroll
    for (int o = 0; o < 6; ++o) {
        float g0, g1;
        cell_w(hs, he, s0h + (float)o, g0, g1);
        wy[o] += g0; wy[o + 1] += g1;
        cell_w(ws, we, s0w + (float)o, g0, g1);
        wx[o] += g0; wx[o + 1] += g1;
    }
    int npy = min(7, max(0, (int)ceilf(he - s0h + 1.0f)));
    int npx = min(7, max(0, (int)ceilf(we - s0w + 1.0f)));
    npy = max(0, min(npy, H_ - h0));
    npx = max(0, min(npx, W_ - w0));

    const float* fbc = f + ((size_t)bb * C_ + c) * (H_ * W_);
    float acc = 0.0f;
#pragma unroll
    for (int dy = 0; dy < 7; ++dy) {
        if (dy < npy) {
            float row = 0.0f;
#pragma unroll
            for (int dx = 0; dx < 7; ++dx) {
                if (dx < npx)
                    row = fmaf(wx[dx], fbc[(h0 + dy) * W_ + (w0 + dx)], row);
            }
            acc = fmaf(wy[dy], row, acc);
        }
    }
    out[oidx] = acc / win;
}

extern "C" void kernel_launch(void* const* d_in, const int* in_sizes, int n_in,
                              void* d_out, int out_size, void* d_ws, size_t ws_size,
                              hipStream_t stream) {
    const float* feat = (const float*)d_in[0];
    const float* rois = (const float*)d_in[1];
    float* out = (float*)d_out;

    const size_t fth_b   = (size_t)B_ * HW_ * C_ * sizeof(__half);    //  8,388,608
    const size_t slack_b = (size_t)SLACKH * sizeof(__half);           //     34,816
    const size_t perm_b  = (size_t)R_ * sizeof(int);                  //      4,096
    const size_t rt_b    = (size_t)R_ * ROIT * sizeof(float);         //    524,288
    const size_t scr_b   = (size_t)R_ * PHW_ * C_ * sizeof(__half);   // 25,690,112

    const size_t base = fth_b + slack_b + perm_b + rt_b;
    if (ws_size >= base + scr_b) {
        __half* fTh  = (__half*)d_ws;
        int*    perm = (int*)((char*)d_ws + fth_b + slack_b);
        float*  rtab = (float*)((char*)d_ws + fth_b + slack_b + perm_b);
        __half* scr  = (__half*)((char*)d_ws + base);
        prep<<<709, 256, 0, stream>>>(feat, fTh, rois, perm, rtab);
        prroi_rows<<<2048, 256, 0, stream>>>(fTh, perm, rtab, scr);
        fixup<<<2048, 256, 0, stream>>>(perm, scr, out);
    } else {
        prroi_pool_direct<<<R_ * PHW_, 256, 0, stream>>>(feat, rois, out);
    }
}

// Round 19
// 57.128 us; speedup vs baseline: 1.0492x; 1.0492x over previous
//
#include <hip/hip_runtime.h>
#include <hip/hip_fp16.h>

#define R_    1024
#define B_    4
#define C_    256
#define H_    64
#define W_    64
#define HW_   4096
#define PHW_  49
#define ROIT  128      // floats per per-ROI wy/meta record (512 B)
#define LROWH 130      // fixup LDS row halves (128 + 2 pad)
#define TROW  260      // prep-transpose LDS row halves (256 + 4 pad)
#define SLACKH 17408   // zeroed halves after fTh (full row + col overrun)

__device__ __forceinline__ void cell_w(float start, float end, float s, float& g0, float& g1) {
    float y0 = fmaxf(start, s);
    float yl = fmaxf(fminf(end, s + 1.0f), y0);
    float a  = y0 - s;
    float la = yl - s;
    g0 = la - 0.5f * la * la - a + 0.5f * a * a;
    g1 = 0.5f * la * la - 0.5f * a * a;
}

// ---- prep: transpose (B,C,H,W) f32 -> (B,H*W,C) f16 [0..511]
//            + ROI sort / slack-zero [512] + per-bin geometry [513..708] ----
__global__ __launch_bounds__(256) void prep(const float* __restrict__ in,
                                            __half* __restrict__ fTh,
                                            const float* __restrict__ rois,
                                            int* __restrict__ perm,
                                            float* __restrict__ roitab) {
    int bid = blockIdx.x;
    if (bid < 512) {
        __shared__ __align__(16) __half lds_t[32 * TROW];
        int b  = bid >> 7;
        int p0 = (bid & 127) * 32;
        int tx = threadIdx.x & 31;
        int ty = threadIdx.x >> 5;
        const float* src = in + (size_t)b * C_ * HW_ + p0 + tx;
#pragma unroll
        for (int i = 0; i < 32; ++i) {
            int c = ty * 32 + i;
            lds_t[tx * TROW + c] = __float2half(src[(size_t)c * HW_]);
        }
        __syncthreads();
#pragma unroll
        for (int u = 0; u < 8; ++u) {
            int e = threadIdx.x + u * 256;
            int p = e >> 6;
            int q = e & 63;
            uint2 v = *(const uint2*)&lds_t[p * TROW + q * 4];
            *(uint2*)(fTh + ((size_t)b * HW_ + p0 + p) * C_ + q * 4) = v;
        }
        return;
    }
    if (bid == 512) {
        if (threadIdx.x >= 64) {
            for (int j = threadIdx.x - 64; j < SLACKH; j += 192)
                fTh[(size_t)B_ * HW_ * C_ + j] = __half(0.0f);
            return;
        }
        // 1 wave: ballot-based stable counting sort by (batch, y-band). Deterministic.
        int lane = threadIdx.x;
        unsigned long long below = (1ull << lane) - 1ull;
        int key[16];
#pragma unroll
        for (int i = 0; i < 16; ++i) {
            int idx = i * 64 + lane;
            const float* roi = rois + idx * 5;
            int b = (int)roi[0];
            float yc = (roi[2] + roi[4]) * 0.5f * 0.0625f;
            int yb = min(3, max(0, (int)(yc * 0.0625f)));
            key[i] = b * 4 + yb;
        }
        int cntk[16];
#pragma unroll
        for (int k = 0; k < 16; ++k) cntk[k] = 0;
        for (int i = 0; i < 16; ++i)
#pragma unroll
            for (int k = 0; k < 16; ++k)
                cntk[k] += __popcll(__ballot(key[i] == k));
        int off[16]; int acc = 0;
#pragma unroll
        for (int k = 0; k < 16; ++k) { off[k] = acc; acc += cntk[k]; }
        for (int i = 0; i < 16; ++i) {
#pragma unroll
            for (int k = 0; k < 16; ++k) {
                unsigned long long m = __ballot(key[i] == k);
                if (key[i] == k)
                    perm[off[k] + __popcll(m & below)] = i * 64 + lane;
                off[k] += __popcll(m);
            }
        }
        return;
    }
    // per-bin geometry -> rtab
    int i = (bid - 513) * 256 + threadIdx.x;   // 0..50175
    int r  = i / PHW_;
    int k  = i - r * PHW_;
    int ph = k / 7, pw = k - ph * 7;
    const float* roi = rois + r * 5;
    int bb = (int)roi[0];
    float x1 = roi[1] * 0.0625f, y1 = roi[2] * 0.0625f;
    float x2 = roi[3] * 0.0625f, y2 = roi[4] * 0.0625f;
    float rw = fmaxf(x2 - x1, 0.0f), rh = fmaxf(y2 - y1, 0.0f);
    float bw = rw / 7.0f, bh = rh / 7.0f;
    float win = bw * bh;
    float* rt = roitab + (size_t)r * ROIT;

    float wy[8], wx[7];
#pragma unroll
    for (int t = 0; t < 7; ++t) { wy[t] = 0.0f; wx[t] = 0.0f; }
    wy[7] = 0.0f;
    int w0 = 0, h0 = 0, npy = 0, w00 = 0;
    float invwin = 0.0f;
    if (win > 0.0f) {
        float ws = x1 + bw * (float)pw, we = ws + bw;
        float hs = y1 + bh * (float)ph, he = hs + bh;
        float s0w = floorf(ws), s0h = floorf(hs);
        w0 = (int)s0w; h0 = (int)s0h;
        w00 = (int)floorf(x1);
#pragma unroll
        for (int o = 0; o < 6; ++o) {
            float g0, g1;
            cell_w(hs, he, s0h + (float)o, g0, g1);
            wy[o] += g0; wy[o + 1] += g1;
            cell_w(ws, we, s0w + (float)o, g0, g1);
            wx[o] += g0; wx[o + 1] += g1;
        }
        npy = min(7, max(0, (int)ceilf(he - s0h + 1.0f)));
        int npx = min(7, max(0, (int)ceilf(we - s0w + 1.0f)));
        npy = max(0, min(npy, H_ - h0));
        npx = max(0, min(npx, W_ - w0));
#pragma unroll
        for (int t = 0; t < 7; ++t) {
            if (t >= npx) wx[t] = 0.0f;
            if (t >= npy) wy[t] = 0.0f;
        }
        invwin = 1.0f / win;
    }
    if (ph == 0) {
#pragma unroll
        for (int t = 0; t < 7; ++t) rt[pw * 7 + t] = wx[t];
        rt[49 + pw] = __int_as_float(w0 - w00);
    }
    if (pw == 0) {
#pragma unroll
        for (int t = 0; t < 8; ++t) rt[72 + ph * 8 + t] = wy[t] * invwin;   // slot 7 = 0
        rt[64 + ph] = __int_as_float(h0 | (npy << 8));
    }
    if (k == 0) {
        int jlim = 0;
        if (win > 0.0f) {
#pragma unroll
            for (int p = 0; p < 7; ++p) {
                float wsp = x1 + bw * (float)p, wep = wsp + bw;
                float s0wp = floorf(wsp);
                int w0p = (int)s0wp;
                int npxp = min(7, max(0, (int)ceilf(wep - s0wp + 1.0f)));
                npxp = max(0, min(npxp, W_ - w0p));
                jlim = max(jlim, (w0p - w00) + npxp);
            }
        }
        rt[63] = __int_as_float(bb | (w00 << 8) | (jlim << 16));
    }
}

// ---- compute: one wave per (ROI, bin-row); two-column dwordx4 loads;
// FULL packed-f16 datapath: y-sum, bin-coefficient APPLY, accumulators and
// cross-half combine all in __half2 (28 acc regs). dy-loop software-pipelined.
__global__ __launch_bounds__(256, 8) void prroi_rows(const __half* __restrict__ fTh,
                                                     const int* __restrict__ perm,
                                                     const float* __restrict__ roitab,
                                                     __half* __restrict__ scr) {
    __shared__ __align__(16) float colw[4][32 * 8];
    int wid  = __builtin_amdgcn_readfirstlane(threadIdx.x >> 6);
    int lane = threadIdx.x & 63;
    float* cwv = colw[wid];
    int bid = blockIdx.x;                 // 2048 blocks
    int xcd = bid & 7;
    int s   = (bid >> 3) * 4 + wid;       // 0..1023 slot within XCD
    if (s >= 896) return;
    int t   = (s & 31) * 28 + (s >> 5);   // stride-spread bijection over [0,896)
    int g   = xcd * 896 + t;
    int rs  = g / 7;
    int ph  = g - rs * 7;
    int r   = __builtin_amdgcn_readfirstlane(perm[rs]);
    const float* rt = roitab + (size_t)r * ROIT;

#pragma unroll
    for (int u = 0; u < 4; ++u) cwv[lane + u * 64] = 0.0f;
    if (lane < 49) {
        int pw = lane / 7;
        int dx = lane - pw * 7;
        float wxv = rt[lane];
        int d = __float_as_int(rt[49 + pw]);
        cwv[(d + dx) * 8 + pw] = wxv;     // unique (col,pw) per lane
    }
    int meta = __float_as_int(rt[63]);
    int bb   = meta & 0xff;
    int w00  = (meta >> 8) & 0xff;
    int jlim = (meta >> 16) & 0xff;
    int hm   = __float_as_int(rt[64 + ph]);
    int h0   = hm & 0xff;
    int npy  = (hm >> 8) & 0xff;
    int npy2 = (npy + 1) & ~1;            // extra row has wy=0; lands in slack
    const float* wyp = rt + 72 + ph * 8;

    int half = lane >> 5;
    int cl   = lane & 31;
    const __half* fr = fTh + ((size_t)bb * HW_ + (size_t)h0 * W_ + w00 + half) * C_ + cl * 8;

    __half2 acc[7][4];                    // 7 bins x 8 channels, packed f16
#pragma unroll
    for (int p = 0; p < 7; ++p)
#pragma unroll
        for (int q = 0; q < 4; ++q) acc[p][q] = __float2half2_rn(0.0f);

    for (int jl = 0; jl < jlim; jl += 2) {
        const float* cw = cwv + (jl + half) * 8;       // 2 addrs/wave -> free broadcast
        float4 c0 = *(const float4*)(cw);              // coefs p0..3 for my column
        float4 c1 = *(const float4*)(cw + 4);          // coefs p4..6
        const __half* cp = fr + (size_t)jl * C_;
        __half2 g0 = __float2half2_rn(0.0f), g1 = g0, g2 = g0, g3 = g0;
        // software-pipelined dy loop: next row-pair prefetched before consuming current
        uint4 va = *(const uint4*)(cp);
        uint4 vb = *(const uint4*)(cp + W_ * C_);
        int dy = 0;
        for (; dy + 2 < npy2; dy += 2) {
            const __half* rn = cp + (size_t)(dy + 2) * (W_ * C_);
            uint4 na = *(const uint4*)(rn);
            uint4 nb = *(const uint4*)(rn + W_ * C_);
            __half2 w0h = __float2half2_rn(wyp[dy]);
            __half2 w1h = __float2half2_rn(wyp[dy + 1]);
            g0 = __hfma2(w0h, *(__half2*)&va.x, g0);
            g1 = __hfma2(w0h, *(__half2*)&va.y, g1);
            g2 = __hfma2(w0h, *(__half2*)&va.z, g2);
            g3 = __hfma2(w0h, *(__half2*)&va.w, g3);
            g0 = __hfma2(w1h, *(__half2*)&vb.x, g0);
            g1 = __hfma2(w1h, *(__half2*)&vb.y, g1);
            g2 = __hfma2(w1h, *(__half2*)&vb.z, g2);
            g3 = __hfma2(w1h, *(__half2*)&vb.w, g3);
            va = na; vb = nb;
        }
        {
            __half2 w0h = __float2half2_rn(wyp[dy]);
            __half2 w1h = __float2half2_rn(wyp[dy + 1]);
            g0 = __hfma2(w0h, *(__half2*)&va.x, g0);
            g1 = __hfma2(w0h, *(__half2*)&va.y, g1);
            g2 = __hfma2(w0h, *(__half2*)&va.z, g2);
            g3 = __hfma2(w0h, *(__half2*)&va.w, g3);
            g0 = __hfma2(w1h, *(__half2*)&vb.x, g0);
            g1 = __hfma2(w1h, *(__half2*)&vb.y, g1);
            g2 = __hfma2(w1h, *(__half2*)&vb.z, g2);
            g3 = __hfma2(w1h, *(__half2*)&vb.w, g3);
        }
        // packed APPLY: 4 pk-fma per bin
#define APPLYH(P, CF) { \
    __half2 ch = __float2half2_rn(CF); \
    acc[P][0] = __hfma2(ch, g0, acc[P][0]); \
    acc[P][1] = __hfma2(ch, g1, acc[P][1]); \
    acc[P][2] = __hfma2(ch, g2, acc[P][2]); \
    acc[P][3] = __hfma2(ch, g3, acc[P][3]); }
        APPLYH(0, c0.x); APPLYH(1, c0.y); APPLYH(2, c0.z); APPLYH(3, c0.w);
        APPLYH(4, c1.x); APPLYH(5, c1.y); APPLYH(6, c1.z);
#undef APPLYH
    }

    // cross-half combine: lane l and l+32 hold same channels, different column parity
#pragma unroll
    for (int p = 0; p < 7; ++p)
#pragma unroll
        for (int q = 0; q < 4; ++q) {
            int uv = __shfl_xor(*(int*)&acc[p][q], 32);
            acc[p][q] = __hadd2(acc[p][q], *(__half2*)&uv);
        }

    // stores: lower half writes bins 0..3, upper half bins 4..6 (already f16)
    __half* sb = scr + ((size_t)r * PHW_ + ph * 7) * C_ + cl * 8;
#pragma unroll
    for (int s4 = 0; s4 < 4; ++s4) {
        const int ihi = (4 + s4 > 6) ? 6 : 4 + s4;
        __half2 q0 = half ? acc[ihi][0] : acc[s4][0];
        __half2 q1 = half ? acc[ihi][1] : acc[s4][1];
        __half2 q2 = half ? acc[ihi][2] : acc[s4][2];
        __half2 q3 = half ? acc[ihi][3] : acc[s4][3];
        int p = half ? 4 + s4 : s4;
        if (p < 7) {
            union { __half2 h2[4]; uint4 u; } pk;
            pk.h2[0] = q0; pk.h2[1] = q1; pk.h2[2] = q2; pk.h2[3] = q3;
            *(uint4*)(sb + (size_t)p * C_) = pk.u;
        }
    }
}

// ---- fixup: 2 blocks per ROI (half channels); [k][c] f16 -> [c][k] f32 via padded LDS ----
__global__ __launch_bounds__(256) void fixup(const int* __restrict__ perm,
                                             const __half* __restrict__ scr,
                                             float* __restrict__ out) {
    __shared__ __align__(4) __half lds_h[PHW_ * LROWH];   // 12,740 B
    int bid  = blockIdx.x;                     // 2048
    int idx  = (bid & 7) * 256 + (bid >> 3);   // XCD-matched: rs>>7 == bid&7
    int rs   = idx >> 1;
    int half = idx & 1;
    int r    = perm[rs];
    const unsigned int* src = (const unsigned int*)(scr + (size_t)r * PHW_ * C_ + half * 128);
    for (int j = threadIdx.x; j < PHW_ * 64; j += 256) {
        int row = j >> 6;
        int col = j & 63;
        *(unsigned int*)&lds_h[row * LROWH + col * 2] = src[(size_t)row * (C_ / 2) + col];
    }
    __syncthreads();
    float* outr = out + (size_t)r * (C_ * PHW_) + (size_t)half * 128 * PHW_;
#pragma unroll 4
    for (int j = threadIdx.x; j < 128 * PHW_; j += 256) {
        int c = j / PHW_;
        int k = j - c * PHW_;
        outr[j] = __half2float(lds_h[k * LROWH + c]);
    }
}

// ---- fallback: original layout, no workspace ----
__global__ __launch_bounds__(256) void prroi_pool_direct(const float* __restrict__ f,
                                                         const float* __restrict__ rois,
                                                         float* __restrict__ out) {
    int bin = blockIdx.x;
    int r  = bin / PHW_;
    int k  = bin - r * PHW_;
    int ph = k / 7;
    int pw = k - ph * 7;
    int c = threadIdx.x;

    const float* roi = rois + r * 5;
    int bb = (int)roi[0];
    float x1 = roi[1] * 0.0625f, y1 = roi[2] * 0.0625f;
    float x2 = roi[3] * 0.0625f, y2 = roi[4] * 0.0625f;
    float rw = fmaxf(x2 - x1, 0.0f), rh = fmaxf(y2 - y1, 0.0f);
    float bw = rw / 7.0f, bh = rh / 7.0f;
    float win = bw * bh;
    size_t oidx = ((size_t)r * C_ + c) * PHW_ + k;
    if (!(win > 0.0f)) { out[oidx] = 0.0f; return; }

    float ws = x1 + bw * (float)pw, we = ws + bw;
    float hs = y1 + bh * (float)ph, he = hs + bh;
    float s0w = floorf(ws), s0h = floorf(hs);
    int w0 = (int)s0w, h0 = (int)s0h;
    float wy[7], wx[7];
#pragma unroll
    for (int t = 0; t < 7; ++t) { wy[t] = 0.0f; wx[t] = 0.0f; }
#pragma unroll
    for (int o = 0; o < 6; ++o) {
        float g0, g1;
        cell_w(hs, he, s0h + (float)o, g0, g1);
        wy[o] += g0; wy[o + 1] += g1;
        cell_w(ws, we, s0w + (float)o, g0, g1);
        wx[o] += g0; wx[o + 1] += g1;
    }
    int npy = min(7, max(0, (int)ceilf(he - s0h + 1.0f)));
    int npx = min(7, max(0, (int)ceilf(we - s0w + 1.0f)));
    npy = max(0, min(npy, H_ - h0));
    npx = max(0, min(npx, W_ - w0));

    const float* fbc = f + ((size_t)bb * C_ + c) * (H_ * W_);
    float acc = 0.0f;
#pragma unroll
    for (int dy = 0; dy < 7; ++dy) {
        if (dy < npy) {
            float row = 0.0f;
#pragma unroll
            for (int dx = 0; dx < 7; ++dx) {
                if (dx < npx)
                    row = fmaf(wx[dx], fbc[(h0 + dy) * W_ + (w0 + dx)], row);
            }
            acc = fmaf(wy[dy], row, acc);
        }
    }
    out[oidx] = acc / win;
}

extern "C" void kernel_launch(void* const* d_in, const int* in_sizes, int n_in,
                              void* d_out, int out_size, void* d_ws, size_t ws_size,
                              hipStream_t stream) {
    const float* feat = (const float*)d_in[0];
    const float* rois = (const float*)d_in[1];
    float* out = (float*)d_out;

    const size_t fth_b   = (size_t)B_ * HW_ * C_ * sizeof(__half);    //  8,388,608
    const size_t slack_b = (size_t)SLACKH * sizeof(__half);           //     34,816
    const size_t perm_b  = (size_t)R_ * sizeof(int);                  //      4,096
    const size_t rt_b    = (size_t)R_ * ROIT * sizeof(float);         //    524,288
    const size_t scr_b   = (size_t)R_ * PHW_ * C_ * sizeof(__half);   // 25,690,112

    const size_t base = fth_b + slack_b + perm_b + rt_b;
    if (ws_size >= base + scr_b) {
        __half* fTh  = (__half*)d_ws;
        int*    perm = (int*)((char*)d_ws + fth_b + slack_b);
        float*  rtab = (float*)((char*)d_ws + fth_b + slack_b + perm_b);
        __half* scr  = (__half*)((char*)d_ws + base);
        prep<<<709, 256, 0, stream>>>(feat, fTh, rois, perm, rtab);
        prroi_rows<<<2048, 256, 0, stream>>>(fTh, perm, rtab, scr);
        fixup<<<2048, 256, 0, stream>>>(perm, scr, out);
    } else {
        prroi_pool_direct<<<R_ * PHW_, 256, 0, stream>>>(feat, rois, out);
    }
}